// Round 1
// baseline (814.214 us; speedup 1.0000x reference)
//
#include <hip/hip_runtime.h>

#define TWO_PI 6.283185307179586f

// ---------------- wavelet decompose: x[b,2n,2n,64,9] -> d,s [b,n,n,64,9] ----------------
__global__ void wavelet_kernel(const float* __restrict__ x,
                               float* __restrict__ d, float* __restrict__ s,
                               const float* __restrict__ ec_d,
                               const float* __restrict__ ec_s,
                               int n, int total)
{
    __shared__ float wd[324], wsm[324];
    for (int i = threadIdx.x; i < 324; i += blockDim.x) { wd[i] = ec_d[i]; wsm[i] = ec_s[i]; }
    __syncthreads();
    int idx = blockIdx.x * blockDim.x + threadIdx.x;
    if (idx >= total) return;
    int it = idx & 63; int tmp = idx >> 6;
    int iy = tmp % n; tmp /= n;
    int ix = tmp % n; int b = tmp / n;
    int n2 = 2 * n;
    const float* base = x + ((((size_t)(b * n2 + 2 * ix) * n2 + 2 * iy) * 64 + it) * 9);
    const float* p0 = base;
    const float* p1 = base + 64 * 9;               // (2ix, 2iy+1)
    const float* p2 = base + (size_t)n2 * 64 * 9;  // (2ix+1, 2iy)
    const float* p3 = p2 + 64 * 9;                 // (2ix+1, 2iy+1)
    float a[36];
    #pragma unroll
    for (int k = 0; k < 9; ++k) { a[k] = p0[k]; a[9+k] = p1[k]; a[18+k] = p2[k]; a[27+k] = p3[k]; }
    size_t ob = (size_t)idx * 9;
    #pragma unroll
    for (int oc = 0; oc < 9; ++oc) {
        float vd = 0.f, vs = 0.f;
        #pragma unroll
        for (int k = 0; k < 36; ++k) { vd += a[k] * wd[k*9+oc]; vs += a[k] * wsm[k*9+oc]; }
        d[ob+oc] = vd; s[ob+oc] = vs;
    }
}

// ------------- conv3d(3,SAME,cross-corr) + bias + ReLU + Linear, optional accumulate -------------
__global__ void conv_lin_kernel(const float* __restrict__ in, float* __restrict__ out,
                                const float* __restrict__ cw, const float* __restrict__ cb,
                                const float* __restrict__ lw, const float* __restrict__ lb,
                                int n, int total, int accumulate)
{
    __shared__ float scw[2187];
    __shared__ float slw[81], scb[9], slb[9];
    for (int i = threadIdx.x; i < 2187; i += blockDim.x) scw[i] = cw[i];
    if (threadIdx.x < 81) slw[threadIdx.x] = lw[threadIdx.x];
    if (threadIdx.x < 9) { scb[threadIdx.x] = cb[threadIdx.x]; slb[threadIdx.x] = lb[threadIdx.x]; }
    __syncthreads();
    int idx = blockIdx.x * blockDim.x + threadIdx.x;
    if (idx >= total) return;
    int it = idx & 63; int tmp = idx >> 6;
    int iy = tmp % n; tmp /= n;
    int ix = tmp % n; int b = tmp / n;
    float acc[9];
    #pragma unroll
    for (int o = 0; o < 9; ++o) acc[o] = scb[o];
    for (int dx = -1; dx <= 1; ++dx) {
        int jx = ix + dx; if (jx < 0 || jx >= n) continue;
        for (int dy = -1; dy <= 1; ++dy) {
            int jy = iy + dy; if (jy < 0 || jy >= n) continue;
            for (int dt = -1; dt <= 1; ++dt) {
                int jt = it + dt; if (jt < 0 || jt >= 64) continue;
                const float* p = in + (((size_t)(b*n + jx) * n + jy) * 64 + jt) * 9;
                int wo = ((dx+1)*3 + (dy+1))*3 + (dt+1);
                float v[9];
                #pragma unroll
                for (int ic = 0; ic < 9; ++ic) v[ic] = p[ic];
                #pragma unroll
                for (int o = 0; o < 9; ++o) {
                    float t2 = 0.f;
                    #pragma unroll
                    for (int ic = 0; ic < 9; ++ic) t2 += v[ic] * scw[(o*9+ic)*27 + wo];
                    acc[o] += t2;
                }
            }
        }
    }
    #pragma unroll
    for (int o = 0; o < 9; ++o) acc[o] = fmaxf(acc[o], 0.f);
    size_t ob = (size_t)idx * 9;
    #pragma unroll
    for (int o2 = 0; o2 < 9; ++o2) {
        float v = slb[o2];
        #pragma unroll
        for (int o = 0; o < 9; ++o) v += acc[o] * slw[o2*9+o];
        if (accumulate) out[ob+o2] += v; else out[ob+o2] = v;
    }
}

// ---------------- forward z DFT: [site,64,9] -> [site, kz(5), ic(9)] complex ----------------
__global__ void fwdz_kernel(const float* __restrict__ in, float2* __restrict__ Fz, int total)
{
    int idx = blockIdx.x * blockDim.x + threadIdx.x;
    if (idx >= total) return;
    int ic = idx % 9; int tmp = idx / 9;
    int kz = tmp % 5; int site = tmp / 5;
    const float* p = in + (size_t)site * 64 * 9 + ic;
    float re = 0.f, im = 0.f;
    for (int it = 0; it < 64; ++it) {
        int m = (kz * it) & 63;
        float sv, cv; __sincosf((TWO_PI / 64.0f) * m, &sv, &cv);
        float v = p[(size_t)it * 9];
        re += v * cv; im -= v * sv;
    }
    Fz[idx] = make_float2(re, im);
}

// ---------------- forward y DFT (kept modes only) ----------------
__global__ void fwdy_kernel(const float2* __restrict__ Fz, float2* __restrict__ Fzy,
                            int n, int L, int l1, int total)
{
    int idx = blockIdx.x * blockDim.x + threadIdx.x;
    if (idx >= total) return;
    int c45 = idx % 45; int tmp = idx / 45;
    int kyI = tmp % L; tmp /= L;
    int ix = tmp % n; int b = tmp / n;
    int ky = (kyI < l1) ? kyI : (n - L + kyI);
    const float2* p = Fz + ((size_t)(b * n + ix) * n) * 45 + c45;
    float re = 0.f, im = 0.f;
    for (int iy = 0; iy < n; ++iy) {
        int m = (ky * iy) & (n - 1);
        float sv, cv; __sincosf((TWO_PI / n) * m, &sv, &cv);
        float2 a = p[(size_t)iy * 45];
        re += a.x * cv + a.y * sv;   // a * e^{-i theta}
        im += a.y * cv - a.x * sv;
    }
    Fzy[idx] = make_float2(re, im);
}

// ---------------- forward x DFT (kept modes only) ----------------
__global__ void fwdx_kernel(const float2* __restrict__ Fzy, float2* __restrict__ F,
                            int n, int L, int l1, int total)
{
    int idx = blockIdx.x * blockDim.x + threadIdx.x;
    if (idx >= total) return;
    int c45 = idx % 45; int tmp = idx / 45;
    int kyI = tmp % L; tmp /= L;
    int kxI = tmp % L; int b = tmp / L;
    int kx = (kxI < l1) ? kxI : (n - L + kxI);
    const float2* p = Fzy + ((size_t)b * n * L) * 45 + (size_t)kyI * 45 + c45;
    float re = 0.f, im = 0.f;
    for (int ix = 0; ix < n; ++ix) {
        int m = (kx * ix) & (n - 1);
        float sv, cv; __sincosf((TWO_PI / n) * m, &sv, &cv);
        float2 a = p[(size_t)ix * L * 45];
        re += a.x * cv + a.y * sv;
        im += a.y * cv - a.x * sv;
    }
    F[idx] = make_float2(re, im);
}

// ------------- per-mode 9x9 complex channel mix with corner priority w4>w3>w2>w1 -------------
__global__ void mix_kernel(const float2* __restrict__ F, float2* __restrict__ M,
                           const float* __restrict__ w1, const float* __restrict__ w2,
                           const float* __restrict__ w3, const float* __restrict__ w4,
                           int n, int L, int l1, int total)
{
    int idx = blockIdx.x * blockDim.x + threadIdx.x;
    if (idx >= total) return;
    int oc = idx % 9; int tmp = idx / 9;
    int kz = tmp % 5; tmp /= 5;
    int kyI = tmp % L; tmp /= L;
    int kxI = tmp % L; int b = tmp / L;
    int kx = (kxI < l1) ? kxI : (n - L + kxI);
    int ky = (kyI < l1) ? kyI : (n - L + kyI);
    bool lx = kx < l1, hx = kx >= n - l1;
    bool ly = ky < l1, hy = ky >= n - l1;
    const float* w; int wx, wy;
    if (hx && hy)      { w = w4; wx = kx - (n - l1); wy = ky - (n - l1); }
    else if (lx && hy) { w = w3; wx = kx;            wy = ky - (n - l1); }
    else if (hx && ly) { w = w2; wx = kx - (n - l1); wy = ky; }
    else               { w = w1; wx = kx;            wy = ky; }
    const float2* p = F + (((size_t)(b * L + kxI) * L + kyI) * 5 + kz) * 9;
    // w layout: [ic(9)][oc(9)][x(5)][y(5)][z(5)][2]
    const float* wb = w + (((size_t)oc * 5 + wx) * 5 + wy) * 10 + kz * 2;
    float re = 0.f, im = 0.f;
    #pragma unroll
    for (int ic = 0; ic < 9; ++ic) {
        float2 a = p[ic];
        float wr = wb[(size_t)ic * 2250];
        float wi = wb[(size_t)ic * 2250 + 1];
        re += a.x * wr - a.y * wi;
        im += a.x * wi + a.y * wr;
    }
    M[idx] = make_float2(re, im);
}

// ---------------- inverse x (zero-padded modes -> full axis) ----------------
__global__ void invx_kernel(const float2* __restrict__ M, float2* __restrict__ G1,
                            int n, int L, int l1, int total)
{
    int idx = blockIdx.x * blockDim.x + threadIdx.x;
    if (idx >= total) return;
    int c45 = idx % 45; int tmp = idx / 45;
    int kyI = tmp % L; tmp /= L;
    int ix = tmp % n; int b = tmp / n;
    const float2* p = M + ((size_t)b * L * L) * 45 + (size_t)kyI * 45 + c45;
    float re = 0.f, im = 0.f;
    for (int kxI = 0; kxI < L; ++kxI) {
        int kx = (kxI < l1) ? kxI : (n - L + kxI);
        int m = (kx * ix) & (n - 1);
        float sv, cv; __sincosf((TWO_PI / n) * m, &sv, &cv);
        float2 a = p[(size_t)kxI * L * 45];
        re += a.x * cv - a.y * sv;   // a * e^{+i theta}
        im += a.x * sv + a.y * cv;
    }
    G1[idx] = make_float2(re, im);
}

// ---------------- inverse y ----------------
__global__ void invy_kernel(const float2* __restrict__ G1, float2* __restrict__ G2,
                            int n, int L, int l1, int total)
{
    int idx = blockIdx.x * blockDim.x + threadIdx.x;
    if (idx >= total) return;
    int c45 = idx % 45; int tmp = idx / 45;
    int iy = tmp % n; tmp /= n;
    int ix = tmp % n; int b = tmp / n;
    const float2* p = G1 + ((size_t)(b * n + ix) * L) * 45 + c45;
    float re = 0.f, im = 0.f;
    for (int kyI = 0; kyI < L; ++kyI) {
        int ky = (kyI < l1) ? kyI : (n - L + kyI);
        int m = (ky * iy) & (n - 1);
        float sv, cv; __sincosf((TWO_PI / n) * m, &sv, &cv);
        float2 a = p[(size_t)kyI * 45];
        re += a.x * cv - a.y * sv;
        im += a.x * sv + a.y * cv;
    }
    G2[idx] = make_float2(re, im);
}

// ---------------- inverse z (c2r, drops Im at kz=0) + ReLU + Linear ----------------
__global__ void invz_relu_lin_kernel(const float2* __restrict__ G2, float* __restrict__ out,
                                     const float* __restrict__ lw, const float* __restrict__ lb,
                                     float inv_norm, int total)
{
    __shared__ float slw[81], slb[9];
    if (threadIdx.x < 81) slw[threadIdx.x] = lw[threadIdx.x];
    if (threadIdx.x < 9) slb[threadIdx.x] = lb[threadIdx.x];
    __syncthreads();
    int idx = blockIdx.x * blockDim.x + threadIdx.x;
    if (idx >= total) return;
    int it = idx & 63; size_t site = (size_t)(idx >> 6);
    const float2* p = G2 + site * 45;
    float y[9];
    #pragma unroll
    for (int oc = 0; oc < 9; ++oc) {
        float v = 0.f;
        #pragma unroll
        for (int kz = 0; kz < 5; ++kz) {
            int m = (kz * it) & 63;
            float sv, cv; __sincosf((TWO_PI / 64.0f) * m, &sv, &cv);
            float2 a = p[kz * 9 + oc];
            float term = a.x * cv - a.y * sv;
            v += (kz == 0 ? 1.0f : 2.0f) * term;
        }
        y[oc] = fmaxf(v * inv_norm, 0.f);
    }
    size_t ob = (size_t)idx * 9;
    #pragma unroll
    for (int o2 = 0; o2 < 9; ++o2) {
        float v = slb[o2];
        #pragma unroll
        for (int oc = 0; oc < 9; ++oc) v += y[oc] * slw[o2*9+oc];
        out[ob + o2] = v;
    }
}

// ---------------- T0 linear on coarsest x ----------------
__global__ void t0_kernel(const float* __restrict__ in, float* __restrict__ out,
                          const float* __restrict__ w, const float* __restrict__ bias, int total)
{
    int idx = blockIdx.x * blockDim.x + threadIdx.x;
    if (idx >= total) return;
    const float* p = in + (size_t)idx * 9;
    float v[9];
    #pragma unroll
    for (int i = 0; i < 9; ++i) v[i] = p[i];
    size_t ob = (size_t)idx * 9;
    #pragma unroll
    for (int o = 0; o < 9; ++o) {
        float r = bias[o];
        #pragma unroll
        for (int i = 0; i < 9; ++i) r += v[i] * w[o*9+i];
        out[ob + o] = r;
    }
}

// ------------- reconstruct: (x+Us | Ud) -> even/odd interleave to [b,2n,2n,64,9] -------------
__global__ void recon_kernel(const float* __restrict__ x, const float* __restrict__ Us,
                             const float* __restrict__ Ud, float* __restrict__ out,
                             const float* __restrict__ ree, const float* __restrict__ reo,
                             const float* __restrict__ roe, const float* __restrict__ roo,
                             int n, int total)
{
    __shared__ float s_m[4][162];
    for (int i = threadIdx.x; i < 162; i += blockDim.x) {
        s_m[0][i] = ree[i]; s_m[1][i] = reo[i]; s_m[2][i] = roe[i]; s_m[3][i] = roo[i];
    }
    __syncthreads();
    int idx = blockIdx.x * blockDim.x + threadIdx.x;
    if (idx >= total) return;
    int it = idx & 63; int tmp = idx >> 6;
    int iy = tmp % n; tmp /= n;
    int ix = tmp % n; int b = tmp / n;
    float v[18];
    size_t ib = (size_t)idx * 9;
    #pragma unroll
    for (int k = 0; k < 9; ++k) { v[k] = x[ib+k] + Us[ib+k]; v[9+k] = Ud[ib+k]; }
    int n2 = 2 * n;
    #pragma unroll
    for (int q = 0; q < 4; ++q) {
        int rx = q >> 1, ry = q & 1;
        size_t ob = ((((size_t)(b * n2 + 2*ix + rx) * n2) + 2*iy + ry) * 64 + it) * 9;
        const float* mm = s_m[q];
        #pragma unroll
        for (int oc = 0; oc < 9; ++oc) {
            float r = 0.f;
            #pragma unroll
            for (int k = 0; k < 18; ++k) r += v[k] * mm[k*9+oc];
            out[ob + oc] = r;
        }
    }
}

extern "C" void kernel_launch(void* const* d_in, const int* in_sizes, int n_in,
                              void* d_out, int out_size, void* d_ws, size_t ws_size,
                              hipStream_t stream)
{
    const float* x0    = (const float*)d_in[0];
    const float* ec_s  = (const float*)d_in[1];
    const float* ec_d  = (const float*)d_in[2];
    const float* rc_ee = (const float*)d_in[3];
    const float* rc_eo = (const float*)d_in[4];
    const float* rc_oe = (const float*)d_in[5];
    const float* rc_oo = (const float*)d_in[6];
    const float* w1    = (const float*)d_in[7];
    const float* w2    = (const float*)d_in[8];
    const float* w3    = (const float*)d_in[9];
    const float* w4    = (const float*)d_in[10];
    const float* A_Lo_w = (const float*)d_in[11];
    const float* A_Lo_b = (const float*)d_in[12];
    const float* B_cw  = (const float*)d_in[13];
    const float* B_cb  = (const float*)d_in[14];
    const float* B_lw  = (const float*)d_in[15];
    const float* B_lb  = (const float*)d_in[16];
    const float* C_cw  = (const float*)d_in[17];
    const float* C_cb  = (const float*)d_in[18];
    const float* C_lw  = (const float*)d_in[19];
    const float* C_lb  = (const float*)d_in[20];
    const float* T0_w  = (const float*)d_in[21];
    const float* T0_b  = (const float*)d_in[22];

    float* ws = (float*)d_ws;
    size_t off = 0;
    auto alloc = [&](size_t nf) { float* p = ws + off; off += (nf + 3) & ~(size_t)3; return p; };

    int ns_[6] = {32, 16, 8, 4, 2, 1};
    size_t Ssz[6];
    float* sb[6]; float* UdB[6]; float* UsB[6];
    for (int i = 0; i < 6; ++i) Ssz[i] = (size_t)8 * ns_[i] * ns_[i] * 64 * 9;
    for (int i = 0; i < 6; ++i) sb[i]  = alloc(Ssz[i]);
    for (int i = 0; i < 6; ++i) UdB[i] = alloc(Ssz[i]);
    for (int i = 0; i < 6; ++i) UsB[i] = alloc(Ssz[i]);
    float* dbuf = alloc(Ssz[0]);
    float2* tA = (float2*)alloc(2 * 368640);  // [8,n,n,5,9] complex, max at n=32
    float2* tB = (float2*)alloc(2 * 115200);  // [8,n,L,5,9]
    float2* tC = (float2*)alloc(2 * 36000);   // [8,L,L,5,9]
    float2* tD = (float2*)alloc(2 * 36000);

    const int BLK = 256;
    for (int lev = 0; lev < 6; ++lev) {
        int n = ns_[lev];
        const float* xin = (lev == 0) ? x0 : sb[lev-1];
        int total = 8 * n * n * 64;
        int nblk = (total + BLK - 1) / BLK;
        wavelet_kernel<<<nblk, BLK, 0, stream>>>(xin, dbuf, sb[lev], ec_d, ec_s, n, total);

        int l1 = (n/2 + 1 < 5) ? (n/2 + 1) : 5;
        int L  = (2*l1 < n) ? 2*l1 : n;
        int t1 = 8 * n * n * 45;
        int t2 = 8 * n * L * 45;
        int t3 = 8 * L * L * 45;
        fwdz_kernel<<<(t1+BLK-1)/BLK, BLK, 0, stream>>>(dbuf, tA, t1);
        fwdy_kernel<<<(t2+BLK-1)/BLK, BLK, 0, stream>>>(tA, tB, n, L, l1, t2);
        fwdx_kernel<<<(t3+BLK-1)/BLK, BLK, 0, stream>>>(tB, tC, n, L, l1, t3);
        mix_kernel <<<(t3+BLK-1)/BLK, BLK, 0, stream>>>(tC, tD, w1, w2, w3, w4, n, L, l1, t3);
        invx_kernel<<<(t2+BLK-1)/BLK, BLK, 0, stream>>>(tD, tB, n, L, l1, t2);
        invy_kernel<<<(t1+BLK-1)/BLK, BLK, 0, stream>>>(tB, tA, n, L, l1, t1);
        invz_relu_lin_kernel<<<nblk, BLK, 0, stream>>>(tA, UdB[lev], A_Lo_w, A_Lo_b,
                                                       1.0f / ((float)n * (float)n * 64.0f), total);
        // Ud += conv_B(s);  Us = conv_C(d)
        conv_lin_kernel<<<nblk, BLK, 0, stream>>>(sb[lev], UdB[lev], B_cw, B_cb, B_lw, B_lb, n, total, 1);
        conv_lin_kernel<<<nblk, BLK, 0, stream>>>(dbuf,    UsB[lev], C_cw, C_cb, C_lw, C_lb, n, total, 0);
    }

    // coarsest-level linear T0 (reuse dbuf, it is free now)
    t0_kernel<<<2, BLK, 0, stream>>>(sb[5], dbuf, T0_w, T0_b, 512);

    float* cur = dbuf;
    for (int lev = 5; lev >= 0; --lev) {
        int n = ns_[lev];
        int total = 8 * n * n * 64;
        float* outp = (lev == 0) ? (float*)d_out : ((cur == dbuf) ? sb[0] : dbuf);
        recon_kernel<<<(total+BLK-1)/BLK, BLK, 0, stream>>>(cur, UsB[lev], UdB[lev], outp,
                                                            rc_ee, rc_eo, rc_oe, rc_oo, n, total);
        cur = outp;
    }
}